// Round 10
// baseline (1265.199 us; speedup 1.0000x reference)
//
#include <hip/hip_runtime.h>
#include <math.h>

// KDC Lindblad propagator — real-basis reduction + fp64 MFMA + sparse Horner.
// f64 16x16x4 C/D layout (HW-probed round 4): col=lane&15, row=(lane>>4)+4*reg.
//
// Round 10 deltas on the validated round-9 skeleton:
//  (a) PA 66 -> 65: LDS row-stride ≡ 1 (mod 16) makes every 16-lane phase of
//      the b64 operand reads hit 16 distinct bank-pairs (was 2-way, 4.2M cyc).
//  (b) dgemm global k-split-2: grid (16,16,2), z-block computes K-half partial
//      -> 2 blocks/CU (32 waves) so LDS and MFMA pipes overlap instead of sum.
//      Squaring chain consumes partials by summing during staging (M0+M1);
//      only V needs an explicit reduce; transpose sums U's partials.
// Pipeline: G16 = I + (tau/8)/16 T; 15 sparse applies -> W = Taylor16(tau T/8);
// U = W^8 (3 split-sq); V = U^32 (5 split-sq); meet-in-middle chains; pops.

#define DS 1024
#define MATD ((size_t)DS * DS * sizeof(double))
#define PA 65

typedef double v4d __attribute__((ext_vector_type(4)));

__device__ inline double Qel(int i, int j) {
    if (i == j + 1) return sqrt((double)i) * 0.70710678118654752440;
    if (j == i + 1) return sqrt((double)j) * 0.70710678118654752440;
    return 0.0;
}

__device__ inline void fill_H(double* Hs, int tid) {
    const double CM2EV = 0.00012398419;
    const double E_S1 = 3.995, E_S2 = 4.9183;
    const double om6a = 596.0 * CM2EV, om10a = 919.0 * CM2EV;
    const double kapA = -0.0964, kapB = 0.1193, lam = 0.1825, gam = -0.018;
    for (int h = tid; h < 1024; h += 256) {
        int r = h >> 5, c = h & 31;
        int e = r >> 4, v6 = (r >> 2) & 3, v10 = r & 3;
        int e2 = c >> 4, w6 = (c >> 2) & 3, w10 = c & 3;
        double val = 0.0;
        if (r == c) val += (e ? E_S2 : E_S1) + om6a * v6 + om10a * v10;
        if (e == e2 && v10 == w10) val += (e ? kapB : kapA) * Qel(v6, w6);
        if (e != e2 && v6 == w6) {
            double q2 = 0.0;
            #pragma unroll
            for (int m = 0; m < 4; ++m) q2 += Qel(v10, m) * Qel(m, w10);
            val += lam * Qel(v10, w10) + gam * q2;
        }
        Hs[h] = val;
    }
}

// --------------------------------------------------------- build G16 --------
__global__ __launch_bounds__(256)
void build_G16(const float* __restrict__ logg, double* __restrict__ X)
{
    __shared__ double Hs[1024];
    int tid = threadIdx.x;
    fill_H(Hs, tid);
    __syncthreads();
    double g = exp((double)logg[0]);
    const double sc = ((1.0 / 0.6582119569) / 8.0) / 16.0;
    int idx = blockIdx.x * 256 + tid;
    int r = idx >> 10, c = idx & 1023;
    int i = r >> 5, j = r & 31;
    int k = c >> 5, l = c & 31;
    double t = 0.0;
    if (k <= l) {
        if (i <= j) {
            if (i < 16 && j < 16) {
                int p = i + 16, q = j + 16;
                if ((p == k && q == l) || (p == l && q == k)) t += g;
            }
            if (i == k && j == l) t -= 0.5 * g * ((i >= 16) + (j >= 16));
        } else {
            if (j == l) t += Hs[i * 32 + k];
            if (k != l && j == k) t += Hs[i * 32 + l];
            if (i == k) t -= Hs[l * 32 + j];
            if (k != l && i == l) t -= Hs[k * 32 + j];
        }
    } else {
        if (i <= j) {
            double ha = 0.0;
            if (j == l) ha += Hs[i * 32 + k];
            if (j == k) ha -= Hs[i * 32 + l];
            if (i == k) ha -= Hs[l * 32 + j];
            if (i == l) ha += Hs[k * 32 + j];
            t -= ha;
        } else {
            if (i < 16 && j < 16 && (i + 16 == k) && (j + 16 == l)) t += g;
            if (i == k && j == l) t -= 0.5 * g * ((i >= 16) + (j >= 16));
        }
    }
    X[idx] = t * sc + ((r == c) ? 1.0 : 0.0);
}

// --------------------------------------------------------- sparse T-apply ---
__global__ __launch_bounds__(256)
void apply_T(const float* __restrict__ logg, const double* __restrict__ M,
             double* __restrict__ O, double invk)
{
    __shared__ double Hs[1024];
    const int tid = threadIdx.x;
    fill_H(Hs, tid);
    __syncthreads();
    const double g = exp((double)logg[0]);
    const double sck = ((1.0 / 0.6582119569) / 8.0) * invk;
    const int p = blockIdx.x;
    const int i = p >> 5, j = p & 31;

    double a0 = 0.0, a1 = 0.0, a2 = 0.0, a3 = 0.0;
    const int e = tid;

#define ADDROW(q, wgt) { const double* r_ = M + (size_t)(q) * DS; double w_ = (wgt); \
    a0 += w_ * r_[e]; a1 += w_ * r_[e + 256];                                        \
    a2 += w_ * r_[e + 512]; a3 += w_ * r_[e + 768]; }

    if (i <= j) {
        for (int m = 0; m < 32; ++m) {
            double c = Hs[i * 32 + m];
            if (c != 0.0 && m != j) {
                if (m > j) ADDROW(m * 32 + j, -c)
                else       ADDROW(j * 32 + m,  c)
            }
        }
        for (int m = 0; m < 32; ++m) {
            double c = Hs[m * 32 + j];
            if (c != 0.0 && m != i) {
                if (i > m) ADDROW(i * 32 + m,  c)
                else       ADDROW(m * 32 + i, -c)
            }
        }
        if (i < 16 && j < 16) ADDROW((i + 16) * 32 + (j + 16), g)
        if (i >= 16 || j >= 16)
            ADDROW(p, -0.5 * g * (double)((i >= 16) + (j >= 16)))
    } else {
        for (int m = 0; m < 32; ++m) {
            double c = Hs[i * 32 + m];
            if (c != 0.0) {
                int lo = m < j ? m : j, hi = m < j ? j : m;
                ADDROW(lo * 32 + hi, c)
            }
        }
        for (int m = 0; m < 32; ++m) {
            double c = Hs[m * 32 + j];
            if (c != 0.0) {
                int lo = m < i ? m : i, hi = m < i ? i : m;
                ADDROW(lo * 32 + hi, -c)
            }
        }
        if (i < 16 && j < 16) ADDROW((i + 16) * 32 + (j + 16), g)
        ADDROW(p, -0.5 * g * (double)((i >= 16) + (j >= 16)))
    }
#undef ADDROW

    size_t base = (size_t)p * DS;
    O[base + e]       = sck * a0 + ((p == e)       ? 1.0 : 0.0);
    O[base + e + 256] = sck * a1 + ((p == e + 256) ? 1.0 : 0.0);
    O[base + e + 512] = sck * a2 + ((p == e + 512) ? 1.0 : 0.0);
    O[base + e + 768] = sck * a3 + ((p == e + 768) ? 1.0 : 0.0);
}

// --------------------------------------------------------- dgemm_sq ---------
// Squaring with k-split-2: M = M0 (+ M1 if non-null); blockIdx.z = k-half;
// Pz = M*M restricted to K in [512z, 512z+512). 64x64 tile, 1024 threads
// (16 waves): 4 output quadrants x 4 k-groups; 3-phase LDS k-reduction.
__global__ __launch_bounds__(1024, 1)
void dgemm_sq(const double* __restrict__ M0, const double* __restrict__ M1,
              double* __restrict__ P0, double* __restrict__ P1)
{
    __shared__ double As[64 * PA];   // [row][k]
    __shared__ double Bs[64 * PA];   // [k][col]
    const int tid = threadIdx.x;
    const int bm = blockIdx.x << 6, bn = blockIdx.y << 6;
    const int kq = blockIdx.z << 9;          // k-half base
    double* D = blockIdx.z ? P1 : P0;
    const int w = tid >> 6, lane = tid & 63;
    const int lr = lane & 15, lk = lane >> 4;
    const int p = w & 3, kg = w >> 2;
    const int wr = (p >> 1) << 5, wc = (p & 1) << 5;

    v4d acc[2][2];
    #pragma unroll
    for (int si = 0; si < 2; ++si)
        #pragma unroll
        for (int sj = 0; sj < 2; ++sj) acc[si][sj] = (v4d){0., 0., 0., 0.};

    const int ra = tid >> 4;          // 0..63
    const int cs = (tid & 15) << 2;   // 0..60
    const size_t offA = (size_t)(bm + ra) * DS + kq + cs;   // A row, k-col
    const size_t offB = (size_t)(kq + ra) * DS + bn + cs;   // B k-row, col
    double va[4], vb[4];
    #pragma unroll
    for (int u = 0; u < 4; ++u) {
        va[u] = M0[offA + u];
        vb[u] = M0[offB + u];
        if (M1) { va[u] += M1[offA + u]; vb[u] += M1[offB + u]; }
    }

    for (int kt = 0; kt < 512; kt += 64) {
        #pragma unroll
        for (int u = 0; u < 4; ++u) {
            As[ra * PA + cs + u] = va[u];
            Bs[ra * PA + cs + u] = vb[u];
        }
        __syncthreads();
        if (kt + 64 < 512) {
            const size_t oa = offA + kt + 64;
            const size_t ob = offB + (size_t)(kt + 64) * DS;
            #pragma unroll
            for (int u = 0; u < 4; ++u) {
                va[u] = M0[oa + u];
                vb[u] = M0[ob + u];
                if (M1) { va[u] += M1[oa + u]; vb[u] += M1[ob + u]; }
            }
        }
        #pragma unroll
        for (int s = 0; s < 4; ++s) {
            int k = (kg << 4) + (s << 2) + lk;
            double a0 = As[(wr + lr) * PA + k];
            double a1 = As[(wr + 16 + lr) * PA + k];
            double b0 = Bs[k * PA + wc + lr];
            double b1 = Bs[k * PA + wc + 16 + lr];
            acc[0][0] = __builtin_amdgcn_mfma_f64_16x16x4f64(a0, b0, acc[0][0], 0, 0, 0);
            acc[0][1] = __builtin_amdgcn_mfma_f64_16x16x4f64(a0, b1, acc[0][1], 0, 0, 0);
            acc[1][0] = __builtin_amdgcn_mfma_f64_16x16x4f64(a1, b0, acc[1][0], 0, 0, 0);
            acc[1][1] = __builtin_amdgcn_mfma_f64_16x16x4f64(a1, b1, acc[1][1], 0, 0, 0);
        }
        __syncthreads();
    }

    double* red = As;   // 64x64
    if (kg == 3) {
        #pragma unroll
        for (int si = 0; si < 2; ++si)
            #pragma unroll
            for (int sj = 0; sj < 2; ++sj)
                #pragma unroll
                for (int r = 0; r < 4; ++r)
                    red[(wr + si * 16 + lk + 4 * r) * 64 + wc + sj * 16 + lr]
                        = acc[si][sj][r];
    }
    __syncthreads();
    if (kg == 2) {
        #pragma unroll
        for (int si = 0; si < 2; ++si)
            #pragma unroll
            for (int sj = 0; sj < 2; ++sj)
                #pragma unroll
                for (int r = 0; r < 4; ++r)
                    red[(wr + si * 16 + lk + 4 * r) * 64 + wc + sj * 16 + lr]
                        += acc[si][sj][r];
    }
    __syncthreads();
    if (kg == 1) {
        #pragma unroll
        for (int si = 0; si < 2; ++si)
            #pragma unroll
            for (int sj = 0; sj < 2; ++sj)
                #pragma unroll
                for (int r = 0; r < 4; ++r)
                    red[(wr + si * 16 + lk + 4 * r) * 64 + wc + sj * 16 + lr]
                        += acc[si][sj][r];
    }
    __syncthreads();
    if (kg == 0) {
        #pragma unroll
        for (int si = 0; si < 2; ++si)
            #pragma unroll
            for (int sj = 0; sj < 2; ++sj) {
                int col = bn + wc + sj * 16 + lr;
                #pragma unroll
                for (int r = 0; r < 4; ++r) {
                    int row = bm + wr + si * 16 + lk + 4 * r;
                    D[(size_t)row * DS + col] = acc[si][sj][r]
                        + red[(wr + si * 16 + lk + 4 * r) * 64 + wc + sj * 16 + lr];
                }
            }
    }
}

// --------------------------------------------------------- reduce -----------
__global__ __launch_bounds__(256)
void reduceAdd(const double* __restrict__ A, const double* __restrict__ B,
               double* __restrict__ O)
{
    int i = blockIdx.x * 256 + threadIdx.x;
    O[i] = A[i] + B[i];
}

// --------------------------------------------------------- transpose + init -
// MT = (M0+M1)^T; blocks 0..11 additionally init Y/Z (disjoint writes).
__global__ __launch_bounds__(256)
void transposeK(const double* __restrict__ M0, const double* __restrict__ M1,
                double* __restrict__ MT, double* __restrict__ Y,
                double* __restrict__ Z)
{
    __shared__ double t[32][33];
    int bx = blockIdx.x << 5, by = blockIdx.y << 5;
    int x = threadIdx.x & 31, y = threadIdx.x >> 5;
    #pragma unroll
    for (int dy = 0; dy < 32; dy += 8) {
        size_t o = (size_t)(by + y + dy) * DS + bx + x;
        t[y + dy][x] = M0[o] + M1[o];
    }
    __syncthreads();
    #pragma unroll
    for (int dy = 0; dy < 32; dy += 8)
        MT[(size_t)(bx + y + dy) * DS + by + x] = t[x][y + dy];

    int fb = (blockIdx.y << 5) | blockIdx.x;
    if (fb < 12) {
        int idx = fb * 256 + threadIdx.x;
        if (idx < 2048) {
            int k = idx >> 10, i = idx & 1023;
            double v = 0.0;
            if (i % 33 == 0) {
                int a = i / 33;
                if ((a < 16) == (k == 0)) v = 1.0;
            }
            Y[idx] = v;
        } else if (idx < 3072) {
            Z[idx - 2048] = (idx == 2048 + 528) ? 1.0 : 0.0;
        }
    }
}

// --------------------------------------------------------- chains -----------
__global__ __launch_bounds__(256)
void chain_step(const double* __restrict__ UT, const double* __restrict__ V,
                const double* __restrict__ Yin, double* __restrict__ Yout,
                const double* __restrict__ Zin, double* __restrict__ Zout)
{
    int gw = blockIdx.x * 4 + (threadIdx.x >> 6);
    int lane = threadIdx.x & 63;
    if (gw < 1024) {
        const double* row = UT + (size_t)gw * DS;
        double s0 = 0.0, s1 = 0.0;
        for (int kk = lane; kk < DS; kk += 64) {
            double m = row[kk];
            s0 += m * Yin[kk];
            s1 += m * Yin[DS + kk];
        }
        #pragma unroll
        for (int off = 32; off; off >>= 1) {
            s0 += __shfl_down(s0, off);
            s1 += __shfl_down(s1, off);
        }
        if (lane == 0) { Yout[gw] = s0; Yout[DS + gw] = s1; }
    } else {
        int r = gw - 1024;
        const double* row = V + (size_t)r * DS;
        double s = 0.0;
        for (int kk = lane; kk < DS; kk += 64) s += row[kk] * Zin[kk];
        #pragma unroll
        for (int off = 32; off; off >>= 1) s += __shfl_down(s, off);
        if (lane == 0) Zout[r] = s;
    }
}

// --------------------------------------------------------- output -----------
__global__ __launch_bounds__(128)
void final_pops(const double* __restrict__ Y, const double* __restrict__ Z,
                float* __restrict__ out, int n)
{
    int t = blockIdx.x;
    int k = threadIdx.x >> 6, lane = threadIdx.x & 63;
    int a = t & 31, j = t >> 5;
    const double* y = Y + (size_t)a * 2048 + (size_t)k * 1024;
    const double* z = Z + (size_t)j * 1024;
    double s = 0.0;
    for (int i = lane; i < 1024; i += 64) s += y[i] * z[i];
    #pragma unroll
    for (int off = 32; off; off >>= 1) s += __shfl_down(s, off);
    if (lane == 0) {
        out[(size_t)(k + 1) * n + t] = (float)s;
        if (k == 0) out[t] = 0.0f;
    }
}

// --------------------------------------------------------- host -------------
extern "C" void kernel_launch(void* const* d_in, const int* in_sizes, int n_in,
                              void* d_out, int out_size, void* d_ws, size_t ws_size,
                              hipStream_t stream)
{
    const float* logg = (const float*)d_in[0];
    float* out = (float*)d_out;
    const int n = out_size / 3;
    (void)in_sizes; (void)n_in; (void)ws_size;

    char* ws = (char*)d_ws;
    double* b0 = (double*)(ws + 0 * MATD);
    double* b1 = (double*)(ws + 1 * MATD);
    double* b2 = (double*)(ws + 2 * MATD);
    double* b3 = (double*)(ws + 3 * MATD);
    double* b4 = (double*)(ws + 4 * MATD);
    double* b5 = (double*)(ws + 5 * MATD);
    double* Y  = (double*)(ws + 6 * MATD);   // 32 x 2 x 1024
    double* Z  = Y + 32 * 2048;              // 32 x 1024

    dim3 gsq(16, 16, 2);
    const double* NUL = nullptr;

    // ---- W = Taylor16(tau*T/8): G16 dense, then 15 sparse applies ----
    build_G16<<<4096, 256, 0, stream>>>(logg, b0);
    double* src = b0; double* dst = b1;
    for (int k = 15; k >= 1; --k) {
        apply_T<<<1024, 256, 0, stream>>>(logg, src, dst, 1.0 / (double)k);
        double* t = src; src = dst; dst = t;
    }
    // W in b1 (b0 scratch/free)

    // ---- squarings with k-split partials (pairs summed during staging) ----
    dgemm_sq<<<gsq, 1024, 0, stream>>>(b1, NUL, b2, b3);  // W^2  -> {b2,b3}
    dgemm_sq<<<gsq, 1024, 0, stream>>>(b2, b3,  b4, b5);  // W^4  -> {b4,b5}
    dgemm_sq<<<gsq, 1024, 0, stream>>>(b4, b5,  b2, b3);  // U=W^8-> {b2,b3} (keep)
    dgemm_sq<<<gsq, 1024, 0, stream>>>(b2, b3,  b0, b1);  // U^2  -> {b0,b1}
    dgemm_sq<<<gsq, 1024, 0, stream>>>(b0, b1,  b4, b5);  // U^4  -> {b4,b5}
    dgemm_sq<<<gsq, 1024, 0, stream>>>(b4, b5,  b0, b1);  // U^8  -> {b0,b1}
    dgemm_sq<<<gsq, 1024, 0, stream>>>(b0, b1,  b4, b5);  // U^16 -> {b4,b5}
    dgemm_sq<<<gsq, 1024, 0, stream>>>(b4, b5,  b0, b1);  // V=U^32->{b0,b1}
    reduceAdd<<<4096, 256, 0, stream>>>(b0, b1, b4);      // V full in b4

    // ---- chains: UT = (U partials summed)^T in b5, init Y/Z merged ----
    transposeK<<<dim3(32, 32), 256, 0, stream>>>(b2, b3, b5, Y, Z);
    for (int a = 1; a < 32; ++a)
        chain_step<<<512, 256, 0, stream>>>(b5, b4,
            Y + (size_t)(a - 1) * 2048, Y + (size_t)a * 2048,
            Z + (size_t)(a - 1) * 1024, Z + (size_t)a * 1024);
    final_pops<<<n, 128, 0, stream>>>(Y, Z, out, n);
}